// Round 8
// baseline (542.013 us; speedup 1.0000x reference)
//
#include <hip/hip_runtime.h>
#include <hip/hip_fp16.h>

// GCN layer: relu(A1·(xW1) + A2·(xW2) + b), B=4, N=50000, F=64, E=800000.
// fp32 in/out, int32 indices. pre stored fp16 (gather operand; fp32 accum).
// Row space concatenated over both supports: srow in [0, 2N); bucket =
// srow/6250 (16 buckets = 2 supports x 8 octants). Build chain:
//   memset -> bin_edges (bucket bin + per-row rank, one int4/edge)
//          -> scan_partial -> scan_sums -> scatter (octant-pinned) 
//   then gemm (pre1/pre2 overwrite the dead bin arrays) -> fused spmm.
#define NB 4
#define NN 50000
#define FF 64
#define NN2 (2 * NN)
#define OCT 6250
#define NBKT 16
#define SCAN_BLOCKS ((NN2 + 255) / 256)   // 391
#define BIN_U 8
#define BIN_T 256
#define BIN_CHUNK (BIN_U * BIN_T)         // 2048 edges per block

// ---------------- fused GEMM: pre{1,2}[n][f] = half4{ x[b][n][:]·W{1,2}[:,f] }
__global__ void gemm_xw2(const float* __restrict__ x,
                         const float* __restrict__ W1, const float* __restrict__ W2,
                         uint2* __restrict__ pre1, uint2* __restrict__ pre2) {
    __shared__ float Ws1[FF][FF];       // 16 KB
    __shared__ float Ws2[FF][FF];       // 16 KB
    __shared__ float xs[16][NB][FF];    // 16 KB  (16 rows x 4 batches)
    const int tid = threadIdx.x;
    const int row0 = blockIdx.x * 16;
#pragma unroll
    for (int i = 0; i < 16; ++i) {
        const int idx = tid + i * 256;
        Ws1[idx >> 6][idx & 63] = W1[idx];
        Ws2[idx >> 6][idx & 63] = W2[idx];
        // x for 16 rows x 4 batches, coalesced 256 B runs:
        const int f = idx & 63, rl = (idx >> 6) & 15, b = idx >> 10;
        xs[rl][b][f] = x[((size_t)b * NN + row0 + rl) * FF + f];
    }
    __syncthreads();                    // single barrier
    const int r = tid >> 6, f = tid & 63;
#pragma unroll
    for (int g = 0; g < 4; ++g) {
        const int rl = g * 4 + r;
        float p0 = 0.f, p1 = 0.f, p2 = 0.f, p3 = 0.f;
        float q0 = 0.f, q1 = 0.f, q2 = 0.f, q3 = 0.f;
#pragma unroll
        for (int k = 0; k < FF; ++k) {
            const float w1 = Ws1[k][f], w2 = Ws2[k][f];          // conflict-free
            const float x0 = xs[rl][0][k], x1 = xs[rl][1][k];    // broadcast
            const float x2 = xs[rl][2][k], x3 = xs[rl][3][k];
            p0 += x0 * w1; p1 += x1 * w1; p2 += x2 * w1; p3 += x3 * w1;
            q0 += x0 * w2; q1 += x1 * w2; q2 += x2 * w2; q3 += x3 * w2;
        }
        const size_t o = (size_t)(row0 + rl) * FF + f;
        __half2 h01 = __floats2half2_rn(p0, p1), h23 = __floats2half2_rn(p2, p3);
        pre1[o] = make_uint2(*(unsigned*)&h01, *(unsigned*)&h23);
        h01 = __floats2half2_rn(q0, q1); h23 = __floats2half2_rn(q2, q3);
        pre2[o] = make_uint2(*(unsigned*)&h01, *(unsigned*)&h23);
    }
}

// ---------------- bin + rank in one pass ------------------------------------
// Per edge: global rank within its row (counts atomic), bucket = srow/OCT,
// block-local counting sort into fixed-capacity bucket arrays; one int4 store
// {srow, rank, col, val} per edge (runs of ~128 edges = 2 KB per bucket).
__global__ void bin_edges_rank(const int* __restrict__ r1, const int* __restrict__ c1,
                               const float* __restrict__ v1,
                               const int* __restrict__ r2, const int* __restrict__ c2,
                               const float* __restrict__ v2,
                               int* __restrict__ counts, int* __restrict__ bcnt,
                               int4* __restrict__ bepack, int cap, int E) {
    __shared__ int lcnt[NBKT], lbase[NBKT];
    const int tid = threadIdx.x;
    if (tid < NBKT) lcnt[tid] = 0;
    __syncthreads();
    const int base = blockIdx.x * BIN_CHUNK;
    int bk[BIN_U], lrk[BIN_U], sr[BIN_U], rk[BIN_U], co[BIN_U], va[BIN_U];
#pragma unroll
    for (int u = 0; u < BIN_U; ++u) {
        const int e = base + u * BIN_T + tid;
        int srow = -1, col = 0, val = 0;
        if (e < E)          { srow = r1[e];          col = c1[e];     val = __float_as_int(v1[e]); }
        else if (e < 2 * E) { srow = NN + r2[e - E]; col = c2[e - E]; val = __float_as_int(v2[e - E]); }
        if (srow >= 0) {
            rk[u] = atomicAdd(&counts[srow], 1);        // global per-row rank
            const int b = srow / OCT;
            bk[u] = b; sr[u] = srow; co[u] = col; va[u] = val;
            lrk[u] = atomicAdd(&lcnt[b], 1);            // LDS, block-local
        } else bk[u] = -1;
    }
    __syncthreads();
    if (tid < NBKT) lbase[tid] = lcnt[tid] ? atomicAdd(&bcnt[tid], lcnt[tid]) : 0;
    __syncthreads();
#pragma unroll
    for (int u = 0; u < BIN_U; ++u) {
        if (bk[u] >= 0) {
            const int pos = bk[u] * cap + lbase[bk[u]] + lrk[u];
            bepack[pos] = make_int4(sr[u], rk[u], co[u], va[u]);
        }
    }
}

// ---------------- hierarchical scan over 2N row counts (partial only) -------
__global__ void scan_partial(const int* __restrict__ counts,
                             int* __restrict__ rowptrP, int* __restrict__ blocksum) {
    __shared__ int buf[256];
    const int tid = threadIdx.x;
    const int i = blockIdx.x * 256 + tid;
    const int v = (i < NN2) ? counts[i] : 0;
    buf[tid] = v;
    __syncthreads();
#pragma unroll
    for (int off = 1; off < 256; off <<= 1) {
        int t = (tid >= off) ? buf[tid - off] : 0;
        __syncthreads();
        buf[tid] += t;
        __syncthreads();
    }
    if (i < NN2) rowptrP[i] = buf[tid] - v;   // exclusive within block
    if (tid == 255) blocksum[blockIdx.x] = buf[255];
}

// Exclusive scan of the 391 block sums, in place.
__global__ void scan_sums(int* __restrict__ blocksum) {
    __shared__ int buf[512];
    const int tid = threadIdx.x;
    const int v = (tid < SCAN_BLOCKS) ? blocksum[tid] : 0;
    buf[tid] = v;
    __syncthreads();
#pragma unroll
    for (int off = 1; off < 512; off <<= 1) {
        int t = (tid >= off) ? buf[tid - off] : 0;
        __syncthreads();
        buf[tid] += t;
        __syncthreads();
    }
    if (tid < SCAN_BLOCKS) blocksum[tid] = buf[tid] - v;
}

// ---------------- scatter, octant-pinned ------------------------------------
// blockIdx%8 = octant; loop s = support. Destination window per octant-pair
// ~3.2 MB (L2-resident under round-robin block->XCD). pos adds blocksum on
// the fly (no scan_add pass).
__global__ void scatter_binned(const int4* __restrict__ bepack, const int* __restrict__ bcnt,
                               const int* __restrict__ rowptrP, const int* __restrict__ blocksum,
                               int2* __restrict__ cv, int cap) {
    const int o = blockIdx.x & 7;
    const int k = blockIdx.x >> 3;
    const int K = gridDim.x >> 3;
#pragma unroll
    for (int s = 0; s < 2; ++s) {
        const int b = s * 8 + o;
        const int beg = b * cap, end = b * cap + bcnt[b];
        for (int i = beg + k * 256 + threadIdx.x; i < end; i += K * 256) {
            const int4 e = bepack[i];     // {srow, rank, col, val}
            const int pos = rowptrP[e.x] + blocksum[e.x >> 8] + e.y;
            cv[pos] = make_int2(e.z, e.w);
        }
    }
}

// ---------------- fused SpMM: out = relu(A1·pre1 + A2·pre2 + b) -------------
__device__ __forceinline__ void acc_seg(int beg, int end,
                                        const int2* __restrict__ cv,
                                        const uint2* __restrict__ pre, int f,
                                        float& a0, float& a1, float& a2, float& a3) {
    int j = beg;
    for (; j + 4 <= end; j += 4) {                 // 4 independent gathers in flight
        const int2 e0 = cv[j], e1 = cv[j + 1], e2 = cv[j + 2], e3 = cv[j + 3];
        const uint2 g0 = pre[(size_t)e0.x * FF + f];
        const uint2 g1 = pre[(size_t)e1.x * FF + f];
        const uint2 g2 = pre[(size_t)e2.x * FF + f];
        const uint2 g3 = pre[(size_t)e3.x * FF + f];
        const float v0 = __int_as_float(e0.y), v1 = __int_as_float(e1.y);
        const float v2 = __int_as_float(e2.y), v3 = __int_as_float(e3.y);
        float2 a, b;
        a = __half22float2(*(const __half2*)&g0.x); b = __half22float2(*(const __half2*)&g0.y);
        a0 += v0 * a.x; a1 += v0 * a.y; a2 += v0 * b.x; a3 += v0 * b.y;
        a = __half22float2(*(const __half2*)&g1.x); b = __half22float2(*(const __half2*)&g1.y);
        a0 += v1 * a.x; a1 += v1 * a.y; a2 += v1 * b.x; a3 += v1 * b.y;
        a = __half22float2(*(const __half2*)&g2.x); b = __half22float2(*(const __half2*)&g2.y);
        a0 += v2 * a.x; a1 += v2 * a.y; a2 += v2 * b.x; a3 += v2 * b.y;
        a = __half22float2(*(const __half2*)&g3.x); b = __half22float2(*(const __half2*)&g3.y);
        a0 += v3 * a.x; a1 += v3 * a.y; a2 += v3 * b.x; a3 += v3 * b.y;
    }
    for (; j < end; ++j) {
        const int2 e = cv[j];
        const uint2 g = pre[(size_t)e.x * FF + f];
        const float v = __int_as_float(e.y);
        const float2 a = __half22float2(*(const __half2*)&g.x);
        const float2 b = __half22float2(*(const __half2*)&g.y);
        a0 += v * a.x; a1 += v * a.y; a2 += v * b.x; a3 += v * b.y;
    }
}

__global__ void spmm_fused(const int* __restrict__ rowptrP, const int* __restrict__ blocksum,
                           const int2* __restrict__ cv,
                           const uint2* __restrict__ pre1, const uint2* __restrict__ pre2,
                           const float* __restrict__ bias, float* __restrict__ out,
                           int totalE) {
    const int tid = blockIdx.x * blockDim.x + threadIdx.x;
    const int r = tid >> 6;
    if (r >= NN) return;
    const int f = tid & 63;
    // final rowptr values (scan_add folded in); wave-uniform -> scalar loads
    const int b0  = rowptrP[r]           + blocksum[r >> 8];
    const int e0_ = rowptrP[r + 1]       + blocksum[(r + 1) >> 8];
    const int b1  = rowptrP[NN + r]      + blocksum[(NN + r) >> 8];
    const int e1_ = (r == NN - 1) ? totalE
                  : rowptrP[NN + r + 1] + blocksum[(NN + r + 1) >> 8];
    float a0 = 0.f, a1 = 0.f, a2 = 0.f, a3 = 0.f;
    acc_seg(b0, e0_, cv, pre1, f, a0, a1, a2, a3);
    acc_seg(b1, e1_, cv, pre2, f, a0, a1, a2, a3);
    const float bf = bias[f];
    a0 += bf; a1 += bf; a2 += bf; a3 += bf;
    const size_t o = (size_t)r * FF + f;
    const size_t s = (size_t)NN * FF;
    out[o]         = a0 > 0.f ? a0 : 0.f;
    out[o + s]     = a1 > 0.f ? a1 : 0.f;
    out[o + 2 * s] = a2 > 0.f ? a2 : 0.f;
    out[o + 3 * s] = a3 > 0.f ? a3 : 0.f;
}

extern "C" void kernel_launch(void* const* d_in, const int* in_sizes, int n_in,
                              void* d_out, int out_size, void* d_ws, size_t ws_size,
                              hipStream_t stream) {
    const float* x     = (const float*)d_in[0];
    const int*   rows1 = (const int*)d_in[1];
    const int*   cols1 = (const int*)d_in[2];
    const float* vals1 = (const float*)d_in[3];
    const int*   rows2 = (const int*)d_in[4];
    const int*   cols2 = (const int*)d_in[5];
    const float* vals2 = (const float*)d_in[6];
    const float* W1    = (const float*)d_in[7];
    const float* W2    = (const float*)d_in[8];
    const float* bias  = (const float*)d_in[9];
    float* out = (float*)d_out;

    const int E = in_sizes[1];
    // Fixed bucket capacity: mean E/8 per bucket, +E/64+4096 (~55 sigma) slack.
    const int cap = E / 8 + E / 64 + 4096;

    // Workspace (~65 MB). Region P (51.2 MB) time-shared:
    //   build : bepack[16*cap] int4 (~30 MB), dead after scatter
    //   compute: pre1 | pre2 (51.2 MB), born at gemm
    char* w = (char*)d_ws;
    auto align = [](size_t v) { return (v + 255) & ~(size_t)255; };
    char* P = w;                                  w += align((size_t)2 * NN * FF * 8);
    int2*  cv       = (int2*)w;                   w += align((size_t)2 * E * 8);
    int*   counts   = (int*)w;                    w += align(((size_t)NN2 + NBKT) * 4);
    int*   rowptrP  = (int*)w;                    w += align(((size_t)NN2 + 1) * 4);
    int*   blocksum = (int*)w;                    w += align((size_t)SCAN_BLOCKS * 4);
    int*   bcnt = counts + NN2;                   // zeroed with counts
    int4*  bepack = (int4*)P;
    uint2* pre1 = (uint2*)P;
    uint2* pre2 = (uint2*)(P + (size_t)NN * FF * 8);

    const int gemm_blocks = NN / 16;                              // 3125
    const int bin_blocks  = (2 * E + BIN_CHUNK - 1) / BIN_CHUNK;  // 782
    const int spmm_blocks = (NN * FF + 255) / 256;                // 12500

    hipMemsetAsync(counts, 0, ((size_t)NN2 + NBKT) * 4, stream);
    bin_edges_rank<<<bin_blocks, BIN_T, 0, stream>>>(rows1, cols1, vals1,
                                                     rows2, cols2, vals2,
                                                     counts, bcnt, bepack, cap, E);
    scan_partial<<<SCAN_BLOCKS, 256, 0, stream>>>(counts, rowptrP, blocksum);
    scan_sums<<<1, 512, 0, stream>>>(blocksum);
    scatter_binned<<<8 * 392, 256, 0, stream>>>(bepack, bcnt, rowptrP, blocksum, cv, cap);
    gemm_xw2<<<gemm_blocks, 256, 0, stream>>>(x, W1, W2, pre1, pre2);
    spmm_fused<<<spmm_blocks, 256, 0, stream>>>(rowptrP, blocksum, cv, pre1, pre2,
                                                bias, out, 2 * E);
}

// Round 9
// 398.343 us; speedup vs baseline: 1.3607x; 1.3607x over previous
//
#include <hip/hip_runtime.h>
#include <hip/hip_fp16.h>

// GCN layer: relu(A1·(xW1) + A2·(xW2) + b), B=4, N=50000, F=64, E=800000.
// fp32 in/out, int32 indices. pre stored fp16 (gather operand; fp32 accum).
// Row space concatenated over both supports: srow in [0, 2N); bucket =
// srow/6250 (16 buckets = 2 supports x 8 octants). Build chain:
//   memset -> bin_edges_rank (bucket bin + per-row rank, one int4/edge)
//          -> scan_partial -> scan_sums -> scatter (octant-pinned)
//   then gemm (pre1/pre2 overwrite the dead bin arrays) -> fused spmm.
// NOTE: gemm_xw2 is the R7 body (36 KB LDS, 4 blocks/CU). The R8 single-
// barrier 48 KB variant regressed 117->240 us (unexplained 830 MB traffic).
#define NB 4
#define NN 50000
#define FF 64
#define NN2 (2 * NN)
#define OCT 6250
#define NBKT 16
#define SCAN_BLOCKS ((NN2 + 255) / 256)   // 391
#define BIN_U 8
#define BIN_T 256
#define BIN_CHUNK (BIN_U * BIN_T)         // 2048 edges per block

// ---------------- fused GEMM: pre{1,2}[n][f] = half4{ x[b][n][:]·W{1,2}[:,f] }
__global__ void gemm_xw2(const float* __restrict__ x,
                         const float* __restrict__ W1, const float* __restrict__ W2,
                         uint2* __restrict__ pre1, uint2* __restrict__ pre2) {
    __shared__ float Ws1[FF][FF];      // 16 KB
    __shared__ float Ws2[FF][FF];      // 16 KB
    __shared__ float xs[NB][4][FF];    // 4 KB
    const int tid = threadIdx.x;
#pragma unroll
    for (int i = 0; i < 16; ++i) {
        int idx = tid + i * 256;
        Ws1[idx >> 6][idx & 63] = W1[idx];
        Ws2[idx >> 6][idx & 63] = W2[idx];
    }
    const int r = tid >> 6, f = tid & 63;
    const int base = blockIdx.x * 16;
#pragma unroll
    for (int g = 0; g < 4; ++g) {
        const int row = base + g * 4 + r;
        __syncthreads();
#pragma unroll
        for (int b = 0; b < NB; ++b)
            xs[b][r][f] = x[((size_t)b * NN + row) * FF + f];   // coalesced
        __syncthreads();
        float p0 = 0.f, p1 = 0.f, p2 = 0.f, p3 = 0.f;
        float q0 = 0.f, q1 = 0.f, q2 = 0.f, q3 = 0.f;
#pragma unroll
        for (int k = 0; k < FF; ++k) {
            const float w1 = Ws1[k][f], w2 = Ws2[k][f];          // conflict-free
            const float x0 = xs[0][r][k], x1 = xs[1][r][k];      // broadcast
            const float x2 = xs[2][r][k], x3 = xs[3][r][k];
            p0 += x0 * w1; p1 += x1 * w1; p2 += x2 * w1; p3 += x3 * w1;
            q0 += x0 * w2; q1 += x1 * w2; q2 += x2 * w2; q3 += x3 * w2;
        }
        const size_t o = (size_t)row * FF + f;
        __half2 h01 = __floats2half2_rn(p0, p1), h23 = __floats2half2_rn(p2, p3);
        pre1[o] = make_uint2(*(unsigned*)&h01, *(unsigned*)&h23);
        h01 = __floats2half2_rn(q0, q1); h23 = __floats2half2_rn(q2, q3);
        pre2[o] = make_uint2(*(unsigned*)&h01, *(unsigned*)&h23);
    }
}

// ---------------- bin + rank in one pass ------------------------------------
__global__ void bin_edges_rank(const int* __restrict__ r1, const int* __restrict__ c1,
                               const float* __restrict__ v1,
                               const int* __restrict__ r2, const int* __restrict__ c2,
                               const float* __restrict__ v2,
                               int* __restrict__ counts, int* __restrict__ bcnt,
                               int4* __restrict__ bepack, int cap, int E) {
    __shared__ int lcnt[NBKT], lbase[NBKT];
    const int tid = threadIdx.x;
    if (tid < NBKT) lcnt[tid] = 0;
    __syncthreads();
    const int base = blockIdx.x * BIN_CHUNK;
    int bk[BIN_U], lrk[BIN_U], sr[BIN_U], rk[BIN_U], co[BIN_U], va[BIN_U];
#pragma unroll
    for (int u = 0; u < BIN_U; ++u) {
        const int e = base + u * BIN_T + tid;
        int srow = -1, col = 0, val = 0;
        if (e < E)          { srow = r1[e];          col = c1[e];     val = __float_as_int(v1[e]); }
        else if (e < 2 * E) { srow = NN + r2[e - E]; col = c2[e - E]; val = __float_as_int(v2[e - E]); }
        if (srow >= 0) {
            rk[u] = atomicAdd(&counts[srow], 1);        // global per-row rank
            const int b = srow / OCT;
            bk[u] = b; sr[u] = srow; co[u] = col; va[u] = val;
            lrk[u] = atomicAdd(&lcnt[b], 1);            // LDS, block-local
        } else bk[u] = -1;
    }
    __syncthreads();
    if (tid < NBKT) lbase[tid] = lcnt[tid] ? atomicAdd(&bcnt[tid], lcnt[tid]) : 0;
    __syncthreads();
#pragma unroll
    for (int u = 0; u < BIN_U; ++u) {
        if (bk[u] >= 0) {
            const int pos = bk[u] * cap + lbase[bk[u]] + lrk[u];
            bepack[pos] = make_int4(sr[u], rk[u], co[u], va[u]);
        }
    }
}

// ---------------- hierarchical scan over 2N row counts (partial only) -------
__global__ void scan_partial(const int* __restrict__ counts,
                             int* __restrict__ rowptrP, int* __restrict__ blocksum) {
    __shared__ int buf[256];
    const int tid = threadIdx.x;
    const int i = blockIdx.x * 256 + tid;
    const int v = (i < NN2) ? counts[i] : 0;
    buf[tid] = v;
    __syncthreads();
#pragma unroll
    for (int off = 1; off < 256; off <<= 1) {
        int t = (tid >= off) ? buf[tid - off] : 0;
        __syncthreads();
        buf[tid] += t;
        __syncthreads();
    }
    if (i < NN2) rowptrP[i] = buf[tid] - v;   // exclusive within block
    if (tid == 255) blocksum[blockIdx.x] = buf[255];
}

// Exclusive scan of the 391 block sums, in place.
__global__ void scan_sums(int* __restrict__ blocksum) {
    __shared__ int buf[512];
    const int tid = threadIdx.x;
    const int v = (tid < SCAN_BLOCKS) ? blocksum[tid] : 0;
    buf[tid] = v;
    __syncthreads();
#pragma unroll
    for (int off = 1; off < 512; off <<= 1) {
        int t = (tid >= off) ? buf[tid - off] : 0;
        __syncthreads();
        buf[tid] += t;
        __syncthreads();
    }
    if (tid < SCAN_BLOCKS) blocksum[tid] = buf[tid] - v;
}

// ---------------- scatter, octant-pinned ------------------------------------
__global__ void scatter_binned(const int4* __restrict__ bepack, const int* __restrict__ bcnt,
                               const int* __restrict__ rowptrP, const int* __restrict__ blocksum,
                               int2* __restrict__ cv, int cap) {
    const int o = blockIdx.x & 7;
    const int k = blockIdx.x >> 3;
    const int K = gridDim.x >> 3;
#pragma unroll
    for (int s = 0; s < 2; ++s) {
        const int b = s * 8 + o;
        const int beg = b * cap, end = b * cap + bcnt[b];
        for (int i = beg + k * 256 + threadIdx.x; i < end; i += K * 256) {
            const int4 e = bepack[i];     // {srow, rank, col, val}
            const int pos = rowptrP[e.x] + blocksum[e.x >> 8] + e.y;
            cv[pos] = make_int2(e.z, e.w);
        }
    }
}

// ---------------- fused SpMM: out = relu(A1·pre1 + A2·pre2 + b) -------------
__device__ __forceinline__ void acc_seg(int beg, int end,
                                        const int2* __restrict__ cv,
                                        const uint2* __restrict__ pre, int f,
                                        float& a0, float& a1, float& a2, float& a3) {
    int j = beg;
    for (; j + 4 <= end; j += 4) {                 // 4 independent gathers in flight
        const int2 e0 = cv[j], e1 = cv[j + 1], e2 = cv[j + 2], e3 = cv[j + 3];
        const uint2 g0 = pre[(size_t)e0.x * FF + f];
        const uint2 g1 = pre[(size_t)e1.x * FF + f];
        const uint2 g2 = pre[(size_t)e2.x * FF + f];
        const uint2 g3 = pre[(size_t)e3.x * FF + f];
        const float v0 = __int_as_float(e0.y), v1 = __int_as_float(e1.y);
        const float v2 = __int_as_float(e2.y), v3 = __int_as_float(e3.y);
        float2 a, b;
        a = __half22float2(*(const __half2*)&g0.x); b = __half22float2(*(const __half2*)&g0.y);
        a0 += v0 * a.x; a1 += v0 * a.y; a2 += v0 * b.x; a3 += v0 * b.y;
        a = __half22float2(*(const __half2*)&g1.x); b = __half22float2(*(const __half2*)&g1.y);
        a0 += v1 * a.x; a1 += v1 * a.y; a2 += v1 * b.x; a3 += v1 * b.y;
        a = __half22float2(*(const __half2*)&g2.x); b = __half22float2(*(const __half2*)&g2.y);
        a0 += v2 * a.x; a1 += v2 * a.y; a2 += v2 * b.x; a3 += v2 * b.y;
        a = __half22float2(*(const __half2*)&g3.x); b = __half22float2(*(const __half2*)&g3.y);
        a0 += v3 * a.x; a1 += v3 * a.y; a2 += v3 * b.x; a3 += v3 * b.y;
    }
    for (; j < end; ++j) {
        const int2 e = cv[j];
        const uint2 g = pre[(size_t)e.x * FF + f];
        const float v = __int_as_float(e.y);
        const float2 a = __half22float2(*(const __half2*)&g.x);
        const float2 b = __half22float2(*(const __half2*)&g.y);
        a0 += v * a.x; a1 += v * a.y; a2 += v * b.x; a3 += v * b.y;
    }
}

__global__ void spmm_fused(const int* __restrict__ rowptrP, const int* __restrict__ blocksum,
                           const int2* __restrict__ cv,
                           const uint2* __restrict__ pre1, const uint2* __restrict__ pre2,
                           const float* __restrict__ bias, float* __restrict__ out,
                           int totalE) {
    const int tid = blockIdx.x * blockDim.x + threadIdx.x;
    const int r = tid >> 6;
    if (r >= NN) return;
    const int f = tid & 63;
    const int b0  = rowptrP[r]           + blocksum[r >> 8];
    const int e0_ = rowptrP[r + 1]       + blocksum[(r + 1) >> 8];
    const int b1  = rowptrP[NN + r]      + blocksum[(NN + r) >> 8];
    const int e1_ = (r == NN - 1) ? totalE
                  : rowptrP[NN + r + 1] + blocksum[(NN + r + 1) >> 8];
    float a0 = 0.f, a1 = 0.f, a2 = 0.f, a3 = 0.f;
    acc_seg(b0, e0_, cv, pre1, f, a0, a1, a2, a3);
    acc_seg(b1, e1_, cv, pre2, f, a0, a1, a2, a3);
    const float bf = bias[f];
    a0 += bf; a1 += bf; a2 += bf; a3 += bf;
    const size_t o = (size_t)r * FF + f;
    const size_t s = (size_t)NN * FF;
    out[o]         = a0 > 0.f ? a0 : 0.f;
    out[o + s]     = a1 > 0.f ? a1 : 0.f;
    out[o + 2 * s] = a2 > 0.f ? a2 : 0.f;
    out[o + 3 * s] = a3 > 0.f ? a3 : 0.f;
}

extern "C" void kernel_launch(void* const* d_in, const int* in_sizes, int n_in,
                              void* d_out, int out_size, void* d_ws, size_t ws_size,
                              hipStream_t stream) {
    const float* x     = (const float*)d_in[0];
    const int*   rows1 = (const int*)d_in[1];
    const int*   cols1 = (const int*)d_in[2];
    const float* vals1 = (const float*)d_in[3];
    const int*   rows2 = (const int*)d_in[4];
    const int*   cols2 = (const int*)d_in[5];
    const float* vals2 = (const float*)d_in[6];
    const float* W1    = (const float*)d_in[7];
    const float* W2    = (const float*)d_in[8];
    const float* bias  = (const float*)d_in[9];
    float* out = (float*)d_out;

    const int E = in_sizes[1];
    const int cap = E / 8 + E / 64 + 4096;   // fixed bucket capacity (huge margin)

    // Workspace (~65 MB). Region P (51.2 MB) time-shared:
    //   build  : bepack[16*cap] int4 (~30 MB), dead after scatter
    //   compute: pre1 | pre2 (51.2 MB), born at gemm
    char* w = (char*)d_ws;
    auto align = [](size_t v) { return (v + 255) & ~(size_t)255; };
    char* P = w;                                  w += align((size_t)2 * NN * FF * 8);
    int2*  cv       = (int2*)w;                   w += align((size_t)2 * E * 8);
    int*   counts   = (int*)w;                    w += align(((size_t)NN2 + NBKT) * 4);
    int*   rowptrP  = (int*)w;                    w += align(((size_t)NN2 + 1) * 4);
    int*   blocksum = (int*)w;                    w += align((size_t)SCAN_BLOCKS * 4);
    int*   bcnt = counts + NN2;                   // zeroed with counts
    int4*  bepack = (int4*)P;
    uint2* pre1 = (uint2*)P;
    uint2* pre2 = (uint2*)(P + (size_t)NN * FF * 8);

    const int gemm_blocks = NN / 16;                              // 3125
    const int bin_blocks  = (2 * E + BIN_CHUNK - 1) / BIN_CHUNK;  // 782
    const int spmm_blocks = (NN * FF + 255) / 256;                // 12500

    hipMemsetAsync(counts, 0, ((size_t)NN2 + NBKT) * 4, stream);
    bin_edges_rank<<<bin_blocks, BIN_T, 0, stream>>>(rows1, cols1, vals1,
                                                     rows2, cols2, vals2,
                                                     counts, bcnt, bepack, cap, E);
    scan_partial<<<SCAN_BLOCKS, 256, 0, stream>>>(counts, rowptrP, blocksum);
    scan_sums<<<1, 512, 0, stream>>>(blocksum);
    scatter_binned<<<8 * 392, 256, 0, stream>>>(bepack, bcnt, rowptrP, blocksum, cv, cap);
    gemm_xw2<<<gemm_blocks, 256, 0, stream>>>(x, W1, W2, pre1, pre2);
    spmm_fused<<<spmm_blocks, 256, 0, stream>>>(rowptrP, blocksum, cv, pre1, pre2,
                                                bias, out, 2 * E);
}